// Round 9
// baseline (652.340 us; speedup 1.0000x reference)
//
#include <hip/hip_runtime.h>
#include <hip/hip_bf16.h>
#include <stdint.h>

typedef short    s16x8  __attribute__((ext_vector_type(8)));
typedef __bf16   bf16x8 __attribute__((ext_vector_type(8)));
typedef float    f32x4  __attribute__((ext_vector_type(4)));

__device__ __forceinline__ unsigned short f2bf(float f) {
    union { float f; unsigned u; } v; v.f = f;
    unsigned r = v.u + 0x7FFFu + ((v.u >> 16) & 1u);
    return (unsigned short)(r >> 16);
}
__device__ __forceinline__ float bf2f(unsigned short s) {
    union { unsigned u; float f; } v; v.u = ((unsigned)s) << 16;
    return v.f;
}

__device__ __forceinline__ void gload16(const void* g, void* l) {
    __builtin_amdgcn_global_load_lds(
        (const __attribute__((address_space(1))) void*)(uintptr_t)g,
        (__attribute__((address_space(3))) void*)(uintptr_t)l,
        16, 0, 0);
}

// ---------------- fp32 -> bf16 conversion (vectorized, grid-stride) ----------
__global__ __launch_bounds__(256) void cvt_bf16(const float* __restrict__ in,
                                                unsigned short* __restrict__ out,
                                                int n4) {
    int i = blockIdx.x * blockDim.x + threadIdx.x;
    int stride = gridDim.x * blockDim.x;
    for (; i < n4; i += stride) {
        const float4 v = *(const float4*)(in + (size_t)i * 4);
        ushort4 o;
        o.x = f2bf(v.x); o.y = f2bf(v.y); o.z = f2bf(v.z); o.w = f2bf(v.w);
        *(ushort4*)(out + (size_t)i * 4) = o;
    }
}

// ---------------- 256x256 bf16 GEMM (round-4 structure) + ABLATION ----------
// VAR bit0 = skip global->LDS staging (and its vmcnt waits become no-ops)
// VAR bit1 = skip per-tile LDS fragment reads (operands loaded once; MFMA
//            dataflow into acc keeps everything live — no DCE)
// VAR==0 is the exact round-4 kernel (correct output).
template<int K, bool OUT_BF16, int VAR>
__global__ __launch_bounds__(512, 2) void gemm256(
        const unsigned short* __restrict__ A,   // [M][K] bf16
        const unsigned short* __restrict__ B,   // [N][K] bf16
        const float* __restrict__ bias,         // [N] fp32
        void* __restrict__ Cvoid,               // [M][N] bf16 or fp32
        int M, int N, int ntn) {
    constexpr int BM = 256, BN = 256, BK = 32, NT = K / BK;
    constexpr bool DO_STAGE = !(VAR & 1);
    constexpr bool DO_DS    = !(VAR & 2);
    __shared__ __align__(16) char smem[131072];           // 128 KiB
    auto As = [&](int t) -> unsigned short* {
        return (unsigned short*)(smem + (t & 3) * 16384);
    };
    auto Bs = [&](int t) -> unsigned short* {
        return (unsigned short*)(smem + 65536 + (t & 3) * 16384);
    };
    const int tid  = threadIdx.x;
    const int lane = tid & 63;
    const int wv   = tid >> 6;
    const int nwg = (int)gridDim.x;
    const int wg  = ((int)blockIdx.x & 7) * (nwg >> 3) + ((int)blockIdx.x >> 3);
    const int bm  = wg / ntn;
    const int bn  = wg % ntn;
    const int wr  = (wv >> 2) * 128;   // wave M-offset in tile
    const int wc  = (wv & 3) * 64;     // wave N-offset in tile
    const int lr  = lane & 15;
    const int ls  = lane >> 4;         // k-slot 0..3

    const unsigned short* Ag = A + (size_t)bm * BM * K;
    const unsigned short* Bg = B + (size_t)bn * BN * K;

    auto stage_half = [&](int t, int h) {
        const unsigned short* GA = Ag + t * BK;
        const unsigned short* GB = Bg + t * BK;
        char* la = (char*)As(t);
        char* lb = (char*)Bs(t);
        const int c     = h * 512 + tid;
        const int row   = c >> 2;                    // 4 x 16B chunks per row
        const int slot  = c & 3;
        const int gslot = slot ^ ((row >> 1) & 3);   // T2 involution
        gload16(GA + (size_t)row * K + gslot * 8, la + c * 16);
        gload16(GB + (size_t)row * K + gslot * 8, lb + c * 16);
    };
    auto frag = [&](const unsigned short* lds, int row) -> bf16x8 {
        const int slot = ls ^ ((row >> 1) & 3);
        return *(const bf16x8*)((const char*)lds + row * (BK * 2) + slot * 16);
    };

    f32x4 acc[8][4] = {};
    bf16x8 bfr[2][4];
    bf16x8 af0[4], af1[4];

    if constexpr (DO_STAGE) {
        stage_half(0, 0); stage_half(0, 1);
        stage_half(1, 0); stage_half(1, 1);
        stage_half(2, 0); stage_half(2, 1);          // 12 loads/thread in flight
        asm volatile("s_waitcnt vmcnt(8)" ::: "memory"); // tile 0 landed
    }
    __builtin_amdgcn_s_barrier();                    // tile 0 published
    #pragma unroll
    for (int n = 0; n < 4; ++n) bfr[0][n] = frag(Bs(0), wc + n * 16 + lr);
    #pragma unroll
    for (int m = 0; m < 4; ++m) af0[m] = frag(As(0), wr + m * 16 + lr);
    if constexpr (!DO_DS) {   // operands fixed for the whole loop: init them all
        #pragma unroll
        for (int n = 0; n < 4; ++n) bfr[1][n] = frag(Bs(0), wc + n * 16 + lr + 8);
        #pragma unroll
        for (int m = 0; m < 4; ++m) af1[m] = frag(As(0), wr + 32 + m * 16 + lr);
    }

    #pragma unroll
    for (int t = 0; t < NT; ++t) {
        const int cur = t & 1, nxt = cur ^ 1;
        // ---- PH0 ----
        if constexpr (DO_STAGE) if (t + 3 < NT) stage_half(t + 3, 0);
        if constexpr (DO_DS) {
            #pragma unroll
            for (int m = 0; m < 4; ++m) af1[m] = frag(As(t), wr + 64 + m * 16 + lr);
        }
        __builtin_amdgcn_s_setprio(1);
        #pragma unroll
        for (int m = 0; m < 4; ++m)
            #pragma unroll
            for (int n = 0; n < 4; ++n)
                acc[m][n] = __builtin_amdgcn_mfma_f32_16x16x32_bf16(
                    af0[m], bfr[cur][n], acc[m][n], 0, 0, 0);
        __builtin_amdgcn_s_setprio(0);
        __builtin_amdgcn_s_barrier();           // [A]

        // ---- PH1 ----
        if constexpr (DO_STAGE) if (t + 3 < NT) stage_half(t + 3, 1);
        if (t + 1 < NT) {
            if constexpr (DO_STAGE) {
                if (t <= NT - 4)      asm volatile("s_waitcnt vmcnt(8)" ::: "memory");
                else if (t == NT - 3) asm volatile("s_waitcnt vmcnt(4)" ::: "memory");
                else                  asm volatile("s_waitcnt vmcnt(0)" ::: "memory");
            }
            __builtin_amdgcn_s_barrier();       // [B]
            if constexpr (DO_DS) {
                #pragma unroll
                for (int n = 0; n < 4; ++n)
                    bfr[nxt][n] = frag(Bs(t + 1), wc + n * 16 + lr);
                #pragma unroll
                for (int m = 0; m < 4; ++m)
                    af0[m] = frag(As(t + 1), wr + m * 16 + lr);
            }
        }
        __builtin_amdgcn_s_setprio(1);
        #pragma unroll
        for (int m = 0; m < 4; ++m)
            #pragma unroll
            for (int n = 0; n < 4; ++n)
                acc[4 + m][n] = __builtin_amdgcn_mfma_f32_16x16x32_bf16(
                    af1[m], bfr[cur][n], acc[4 + m][n], 0, 0, 0);
        __builtin_amdgcn_s_setprio(0);
        __builtin_amdgcn_s_barrier();           // [C]
    }

    // epilogue: C/D layout col=lane&15, row=(lane>>4)*4+j (HW-verified)
    const int r0 = bm * BM + wr + ls * 4;
    const int c0 = bn * BN + wc + lr;
    #pragma unroll
    for (int n = 0; n < 4; ++n) {
        const int gc = c0 + n * 16;
        const float bv = bias[gc];
        #pragma unroll
        for (int m = 0; m < 8; ++m) {
            #pragma unroll
            for (int j = 0; j < 4; ++j) {
                const int gr = r0 + m * 16 + j;
                const float v = acc[m][n][j] + bv;
                if constexpr (OUT_BF16)
                    ((unsigned short*)Cvoid)[(size_t)gr * N + gc] = f2bf(v);
                else
                    ((float*)Cvoid)[(size_t)gr * N + gc] = v;
            }
        }
    }
}

// ---------------- per-token attention over heads (8x8 softmax) --------------
__global__ __launch_bounds__(256) void attn_heads(
        const unsigned short* __restrict__ qkv,   // [M][1536] bf16
        unsigned short* __restrict__ val,         // [M][512]  bf16
        int M) {
    const int t    = blockIdx.x * 4 + (threadIdx.x >> 6);
    const int lane = threadIdx.x & 63;
    const int h    = lane >> 3;
    const int c    = lane & 7;
    const unsigned short* base = qkv + (size_t)t * 1536;

    s16x8 q8 = *(const s16x8*)(base + h * 192 + c * 8);
    float qf[8];
    #pragma unroll
    for (int j = 0; j < 8; ++j) qf[j] = bf2f((unsigned short)q8[j]);

    float s[8];
    #pragma unroll
    for (int g = 0; g < 8; ++g) {
        s16x8 k8 = *(const s16x8*)(base + g * 192 + 64 + c * 8);
        float p = 0.f;
        #pragma unroll
        for (int j = 0; j < 8; ++j) p += qf[j] * bf2f((unsigned short)k8[j]);
        s[g] = p;
    }
    #pragma unroll
    for (int mask = 1; mask <= 4; mask <<= 1)
        #pragma unroll
        for (int g = 0; g < 8; ++g)
            s[g] += __shfl_xor(s[g], mask, 64);

    float mx = -1e30f;
    #pragma unroll
    for (int g = 0; g < 8; ++g) { s[g] *= 0.125f; mx = fmaxf(mx, s[g]); }
    float sum = 0.f;
    #pragma unroll
    for (int g = 0; g < 8; ++g) { s[g] = __expf(s[g] - mx); sum += s[g]; }
    const float inv = 1.f / sum;

    float acc[8] = {0.f,0.f,0.f,0.f,0.f,0.f,0.f,0.f};
    #pragma unroll
    for (int g = 0; g < 8; ++g) {
        s16x8 v8 = *(const s16x8*)(base + g * 192 + 128 + c * 8);
        const float ag = s[g] * inv;
        #pragma unroll
        for (int j = 0; j < 8; ++j) acc[j] += ag * bf2f((unsigned short)v8[j]);
    }
    s16x8 ov;
    #pragma unroll
    for (int j = 0; j < 8; ++j) ov[j] = (short)f2bf(acc[j]);
    *(s16x8*)(val + (size_t)t * 512 + h * 64 + c * 8) = ov;
}

// ---------------------------------------------------------------------------
extern "C" void kernel_launch(void* const* d_in, const int* in_sizes, int n_in,
                              void* d_out, int out_size, void* d_ws, size_t ws_size,
                              hipStream_t stream) {
    const float* x     = (const float*)d_in[0];
    const float* w_qkv = (const float*)d_in[1];
    const float* b_qkv = (const float*)d_in[2];
    const float* w_out = (const float*)d_in[3];
    const float* b_out = (const float*)d_in[4];
    float* out = (float*)d_out;

    const int DM = 512;
    const int M  = in_sizes[0] / DM;      // 61440 tokens

    unsigned short* xb    = (unsigned short*)d_ws;          // M*512
    unsigned short* wqkvb = xb + (size_t)M * DM;            // 1536*512
    unsigned short* woutb = wqkvb + (size_t)3 * DM * DM;    // 512*512
    unsigned short* qkvb  = woutb + (size_t)DM * DM;        // M*1536
    unsigned short* valb  = xb;   // reuse x_bf16 buffer after GEMM1 consumed it

    cvt_bf16<<<2048, 256, 0, stream>>>(x, xb, M * DM / 4);
    cvt_bf16<<<96,   256, 0, stream>>>(w_qkv, wqkvb, 3 * DM * DM / 4);
    cvt_bf16<<<32,   256, 0, stream>>>(w_out, woutb, DM * DM / 4);

    const dim3 g1((M / 256) * (3 * DM / 256));   // 1440

    // ======= ABLATION (diagnostic round): variants write garbage into =======
    // ======= qkvb; the FULL variant runs LAST and overwrites every elem ======
    gemm256<512, true, 1><<<g1, 512, 0, stream>>>(   // V1: no staging
        xb, wqkvb, b_qkv, qkvb, M, 3 * DM, 3 * DM / 256);
    gemm256<512, true, 2><<<g1, 512, 0, stream>>>(   // V2: no per-tile ds_reads
        xb, wqkvb, b_qkv, qkvb, M, 3 * DM, 3 * DM / 256);
    gemm256<512, true, 3><<<g1, 512, 0, stream>>>(   // V3: neither (MFMA floor)
        xb, wqkvb, b_qkv, qkvb, M, 3 * DM, 3 * DM / 256);
    gemm256<512, true, 0><<<g1, 512, 0, stream>>>(   // V0: FULL (correct)
        xb, wqkvb, b_qkv, qkvb, M, 3 * DM, 3 * DM / 256);

    // per-token attention over heads
    attn_heads<<<M / 4, 256, 0, stream>>>(qkvb, valb, M);

    // GEMM2: out[M][512] = val @ w_out^T + b_out (fp32 out). grid 240*2=480
    gemm256<512, false, 0><<<dim3((M / 256) * (DM / 256)), 512, 0, stream>>>(
        valb, woutb, b_out, out, M, DM, DM / 256);
}

// Round 10
// 271.740 us; speedup vs baseline: 2.4006x; 2.4006x over previous
//
#include <hip/hip_runtime.h>
#include <hip/hip_bf16.h>
#include <stdint.h>

typedef short    s16x8  __attribute__((ext_vector_type(8)));
typedef __bf16   bf16x8 __attribute__((ext_vector_type(8)));
typedef float    f32x4  __attribute__((ext_vector_type(4)));

__device__ __forceinline__ unsigned short f2bf(float f) {
    union { float f; unsigned u; } v; v.f = f;
    unsigned r = v.u + 0x7FFFu + ((v.u >> 16) & 1u);
    return (unsigned short)(r >> 16);
}
__device__ __forceinline__ float bf2f(unsigned short s) {
    union { unsigned u; float f; } v; v.u = ((unsigned)s) << 16;
    return v.f;
}

__device__ __forceinline__ void gload16(const void* g, void* l) {
    __builtin_amdgcn_global_load_lds(
        (const __attribute__((address_space(1))) void*)(uintptr_t)g,
        (__attribute__((address_space(3))) void*)(uintptr_t)l,
        16, 0, 0);
}

// ---------------- fp32 -> bf16 conversion (vectorized, grid-stride) ----------
__global__ __launch_bounds__(256) void cvt_bf16(const float* __restrict__ in,
                                                unsigned short* __restrict__ out,
                                                int n4) {
    int i = blockIdx.x * blockDim.x + threadIdx.x;
    int stride = gridDim.x * blockDim.x;
    for (; i < n4; i += stride) {
        const float4 v = *(const float4*)(in + (size_t)i * 4);
        ushort4 o;
        o.x = f2bf(v.x); o.y = f2bf(v.y); o.z = f2bf(v.z); o.w = f2bf(v.w);
        *(ushort4*)(out + (size_t)i * 4) = o;
    }
}

// ---------------- 128x128 bf16 GEMM, OCCUPANCY-FIRST --------------------------
// 4 waves (2x2), 64x64 C per wave (acc = 64 regs), total regs ~115 <= 128
// -> 4 waves/SIMD; LDS 32 KiB double-buffer -> 4 blocks/CU RESIDENT.
// Cross-block TLP hides prologue/epilogue/staging stalls that the previous
// 1-block/CU 256^2 kernels exposed (R2-R8: 248 regs/wave -> 2 waves/SIMD).
// One vmcnt(0) + __syncthreads per K-tile (drain is free: nothing newer in
// flight at that point; syncthreads gives a safe compiler/memory fence).
// T1 XCD swizzle, T2 source-XOR LDS swizzle (conflicts measured 0), T5 setprio.
template<int K, bool OUT_BF16>
__global__ __launch_bounds__(256, 4) void gemm128(
        const unsigned short* __restrict__ A,   // [M][K] bf16
        const unsigned short* __restrict__ B,   // [N][K] bf16
        const float* __restrict__ bias,         // [N] fp32
        void* __restrict__ Cvoid,               // [M][N] bf16 or fp32
        int M, int N, int ntn) {
    constexpr int BM = 128, BN = 128, BK = 32, NT = K / BK;
    __shared__ __align__(16) unsigned short As[2][BM * BK];   // 2 x 8 KiB
    __shared__ __align__(16) unsigned short Bs[2][BN * BK];   // 2 x 8 KiB
    const int tid  = threadIdx.x;
    const int lane = tid & 63;
    const int wv   = tid >> 6;                  // 4 waves
    const int nwg  = (int)gridDim.x;
    const int wg   = ((int)blockIdx.x & 7) * (nwg >> 3) + ((int)blockIdx.x >> 3);
    const int bm   = wg / ntn;
    const int bn   = wg % ntn;
    const int wr   = (wv >> 1) * 64;    // wave M-offset in tile
    const int wc   = (wv & 1) * 64;     // wave N-offset in tile
    const int lr   = lane & 15;
    const int ls   = lane >> 4;         // k-slot 0..3

    const unsigned short* Ag = A + (size_t)bm * BM * K;
    const unsigned short* Bg = B + (size_t)bn * BN * K;

    // Stage K-slab t: A and B 128x32 tiles (8 KiB = 512 x 16B chunks each;
    // 2 chunks/thread/matrix). Linear LDS dest; T2 swizzle on global source.
    auto stage = [&](int t) {
        char* la = (char*)As[t & 1];
        char* lb = (char*)Bs[t & 1];
        #pragma unroll
        for (int p = 0; p < 2; ++p) {
            const int c     = p * 256 + tid;
            const int row   = c >> 2;                    // 4 x 16B chunks per row
            const int slot  = c & 3;
            const int gslot = slot ^ ((row >> 1) & 3);   // T2 involution
            gload16(Ag + (size_t)row * K + t * BK + gslot * 8, la + c * 16);
            gload16(Bg + (size_t)row * K + t * BK + gslot * 8, lb + c * 16);
        }
    };
    auto frag = [&](const unsigned short* lds, int row) -> bf16x8 {
        const int slot = ls ^ ((row >> 1) & 3);
        return *(const bf16x8*)((const char*)lds + row * (BK * 2) + slot * 16);
    };

    f32x4 acc[4][4] = {};

    stage(0);

    #pragma unroll
    for (int t = 0; t < NT; ++t) {
        asm volatile("s_waitcnt vmcnt(0)" ::: "memory");  // own slab-t chunks done
        __syncthreads();               // all waves' chunks visible; prev slab
                                       // fully consumed (reads precede barrier)
        if (t + 1 < NT) stage(t + 1);  // overwrites slab read at iter t-1: safe

        bf16x8 af[4], bf[4];
        #pragma unroll
        for (int m = 0; m < 4; ++m) af[m] = frag(As[t & 1], wr + m * 16 + lr);
        #pragma unroll
        for (int n = 0; n < 4; ++n) bf[n] = frag(Bs[t & 1], wc + n * 16 + lr);

        __builtin_amdgcn_s_setprio(1);
        #pragma unroll
        for (int m = 0; m < 4; ++m)
            #pragma unroll
            for (int n = 0; n < 4; ++n)
                acc[m][n] = __builtin_amdgcn_mfma_f32_16x16x32_bf16(
                    af[m], bf[n], acc[m][n], 0, 0, 0);
        __builtin_amdgcn_s_setprio(0);
    }

    // epilogue: C/D layout col=lane&15, row=(lane>>4)*4+j (HW-verified)
    const int r0 = bm * BM + wr + ls * 4;
    const int c0 = bn * BN + wc + lr;
    #pragma unroll
    for (int n = 0; n < 4; ++n) {
        const int gc = c0 + n * 16;
        const float bv = bias[gc];
        #pragma unroll
        for (int m = 0; m < 4; ++m) {
            #pragma unroll
            for (int j = 0; j < 4; ++j) {
                const int gr = r0 + m * 16 + j;
                const float v = acc[m][n][j] + bv;
                if constexpr (OUT_BF16)
                    ((unsigned short*)Cvoid)[(size_t)gr * N + gc] = f2bf(v);
                else
                    ((float*)Cvoid)[(size_t)gr * N + gc] = v;
            }
        }
    }
}

// ---------------- per-token attention over heads (8x8 softmax) --------------
__global__ __launch_bounds__(256) void attn_heads(
        const unsigned short* __restrict__ qkv,   // [M][1536] bf16
        unsigned short* __restrict__ val,         // [M][512]  bf16
        int M) {
    const int t    = blockIdx.x * 4 + (threadIdx.x >> 6);
    const int lane = threadIdx.x & 63;
    const int h    = lane >> 3;
    const int c    = lane & 7;
    const unsigned short* base = qkv + (size_t)t * 1536;

    s16x8 q8 = *(const s16x8*)(base + h * 192 + c * 8);
    float qf[8];
    #pragma unroll
    for (int j = 0; j < 8; ++j) qf[j] = bf2f((unsigned short)q8[j]);

    float s[8];
    #pragma unroll
    for (int g = 0; g < 8; ++g) {
        s16x8 k8 = *(const s16x8*)(base + g * 192 + 64 + c * 8);
        float p = 0.f;
        #pragma unroll
        for (int j = 0; j < 8; ++j) p += qf[j] * bf2f((unsigned short)k8[j]);
        s[g] = p;
    }
    #pragma unroll
    for (int mask = 1; mask <= 4; mask <<= 1)
        #pragma unroll
        for (int g = 0; g < 8; ++g)
            s[g] += __shfl_xor(s[g], mask, 64);

    float mx = -1e30f;
    #pragma unroll
    for (int g = 0; g < 8; ++g) { s[g] *= 0.125f; mx = fmaxf(mx, s[g]); }
    float sum = 0.f;
    #pragma unroll
    for (int g = 0; g < 8; ++g) { s[g] = __expf(s[g] - mx); sum += s[g]; }
    const float inv = 1.f / sum;

    float acc[8] = {0.f,0.f,0.f,0.f,0.f,0.f,0.f,0.f};
    #pragma unroll
    for (int g = 0; g < 8; ++g) {
        s16x8 v8 = *(const s16x8*)(base + g * 192 + 128 + c * 8);
        const float ag = s[g] * inv;
        #pragma unroll
        for (int j = 0; j < 8; ++j) acc[j] += ag * bf2f((unsigned short)v8[j]);
    }
    s16x8 ov;
    #pragma unroll
    for (int j = 0; j < 8; ++j) ov[j] = (short)f2bf(acc[j]);
    *(s16x8*)(val + (size_t)t * 512 + h * 64 + c * 8) = ov;
}

// ---------------------------------------------------------------------------
extern "C" void kernel_launch(void* const* d_in, const int* in_sizes, int n_in,
                              void* d_out, int out_size, void* d_ws, size_t ws_size,
                              hipStream_t stream) {
    const float* x     = (const float*)d_in[0];
    const float* w_qkv = (const float*)d_in[1];
    const float* b_qkv = (const float*)d_in[2];
    const float* w_out = (const float*)d_in[3];
    const float* b_out = (const float*)d_in[4];
    float* out = (float*)d_out;

    const int DM = 512;
    const int M  = in_sizes[0] / DM;      // 61440 tokens

    unsigned short* xb    = (unsigned short*)d_ws;          // M*512
    unsigned short* wqkvb = xb + (size_t)M * DM;            // 1536*512
    unsigned short* woutb = wqkvb + (size_t)3 * DM * DM;    // 512*512
    unsigned short* qkvb  = woutb + (size_t)DM * DM;        // M*1536
    unsigned short* valb  = xb;   // reuse x_bf16 buffer after GEMM1 consumed it

    cvt_bf16<<<2048, 256, 0, stream>>>(x, xb, M * DM / 4);
    cvt_bf16<<<96,   256, 0, stream>>>(w_qkv, wqkvb, 3 * DM * DM / 4);
    cvt_bf16<<<32,   256, 0, stream>>>(w_out, woutb, DM * DM / 4);

    // GEMM1: qkv[M][1536] = x @ w_qkv^T + b_qkv (bf16 out). grid 480*12=5760
    gemm128<512, true><<<dim3((M / 128) * (3 * DM / 128)), 256, 0, stream>>>(
        xb, wqkvb, b_qkv, qkvb, M, 3 * DM, 3 * DM / 128);

    // per-token attention over heads
    attn_heads<<<M / 4, 256, 0, stream>>>(qkvb, valb, M);

    // GEMM2: out[M][512] = val @ w_out^T + b_out (fp32 out). grid 480*4=1920
    gemm128<512, false><<<dim3((M / 128) * (DM / 128)), 256, 0, stream>>>(
        valb, woutb, b_out, out, M, DM, DM / 128);
}

// Round 11
// 256.394 us; speedup vs baseline: 2.5443x; 1.0599x over previous
//
#include <hip/hip_runtime.h>
#include <hip/hip_bf16.h>
#include <stdint.h>

typedef short    s16x8  __attribute__((ext_vector_type(8)));
typedef __bf16   bf16x8 __attribute__((ext_vector_type(8)));
typedef float    f32x4  __attribute__((ext_vector_type(4)));

__device__ __forceinline__ unsigned short f2bf(float f) {
    union { float f; unsigned u; } v; v.f = f;
    unsigned r = v.u + 0x7FFFu + ((v.u >> 16) & 1u);
    return (unsigned short)(r >> 16);
}
__device__ __forceinline__ float bf2f(unsigned short s) {
    union { unsigned u; float f; } v; v.u = ((unsigned)s) << 16;
    return v.f;
}

__device__ __forceinline__ void gload16(const void* g, void* l) {
    __builtin_amdgcn_global_load_lds(
        (const __attribute__((address_space(1))) void*)(uintptr_t)g,
        (__attribute__((address_space(3))) void*)(uintptr_t)l,
        16, 0, 0);
}

// ---------------- fp32 -> bf16 conversion (vectorized, grid-stride) ----------
__global__ __launch_bounds__(256) void cvt_bf16(const float* __restrict__ in,
                                                unsigned short* __restrict__ out,
                                                int n4) {
    int i = blockIdx.x * blockDim.x + threadIdx.x;
    int stride = gridDim.x * blockDim.x;
    for (; i < n4; i += stride) {
        const float4 v = *(const float4*)(in + (size_t)i * 4);
        ushort4 o;
        o.x = f2bf(v.x); o.y = f2bf(v.y); o.z = f2bf(v.z); o.w = f2bf(v.w);
        *(ushort4*)(out + (size_t)i * 4) = o;
    }
}

// ---------------- 128x128 bf16 GEMM, BK=64 ----------------------------------
// Round-10 structure (4 waves 2x2, 64x64/wave, 1 syncthreads+vmcnt(0) per
// K-tile, T1 XCD swizzle, T2 swizzle, T5 setprio) with BK doubled 32->64:
// NT=8 barrier windows instead of 16 — halves the per-tile fixed costs
// (barrier straggler sync, drain, stage issue) that R10's model identified
// as the dominant residual (952 cyc wall vs 310 cyc MFMA per wave-tile).
// LDS 64 KiB dbuf -> 2 blocks/CU (occupancy traded for amortization).
// Swizzle at BK=64: 8 slots/row, gslot = slot ^ (row & 7); 16-row frag reads
// spread across 8 banks-groups, residual 2-way alias is free (m136).
template<int K, bool OUT_BF16>
__global__ __launch_bounds__(256, 2) void gemm128(
        const unsigned short* __restrict__ A,   // [M][K] bf16
        const unsigned short* __restrict__ B,   // [N][K] bf16
        const float* __restrict__ bias,         // [N] fp32
        void* __restrict__ Cvoid,               // [M][N] bf16 or fp32
        int M, int N, int ntn) {
    constexpr int BM = 128, BN = 128, BK = 64, NT = K / BK;   // NT = 8
    __shared__ __align__(16) unsigned short As[2][BM * BK];   // 2 x 16 KiB
    __shared__ __align__(16) unsigned short Bs[2][BN * BK];   // 2 x 16 KiB
    const int tid  = threadIdx.x;
    const int lane = tid & 63;
    const int wv   = tid >> 6;                  // 4 waves
    const int nwg  = (int)gridDim.x;
    const int wg   = ((int)blockIdx.x & 7) * (nwg >> 3) + ((int)blockIdx.x >> 3);
    const int bm   = wg / ntn;
    const int bn   = wg % ntn;
    const int wr   = (wv >> 1) * 64;    // wave M-offset in tile
    const int wc   = (wv & 1) * 64;     // wave N-offset in tile
    const int lr   = lane & 15;
    const int ls   = lane >> 4;         // k-slot 0..3 within a 32-col half

    const unsigned short* Ag = A + (size_t)bm * BM * K;
    const unsigned short* Bg = B + (size_t)bn * BN * K;

    // Stage K-slab t: A and B 128x64 tiles (16 KiB = 1024 x 16B chunks each;
    // 4 chunks/thread/matrix). Linear LDS dest; T2 swizzle on global source:
    // row has 8 chunks, gslot = slot ^ (row & 7)  (involution, both sides).
    auto stage = [&](int t) {
        char* la = (char*)As[t & 1];
        char* lb = (char*)Bs[t & 1];
        #pragma unroll
        for (int p = 0; p < 4; ++p) {
            const int c     = p * 256 + tid;
            const int row   = c >> 3;                  // 8 x 16B chunks per row
            const int slot  = c & 7;
            const int gslot = slot ^ (row & 7);        // T2 involution
            gload16(Ag + (size_t)row * K + t * BK + gslot * 8, la + c * 16);
            gload16(Bg + (size_t)row * K + t * BK + gslot * 8, lb + c * 16);
        }
    };
    // Fragment read: logical k-slot ks (0..7 = half*4 + ls), physical XOR'd.
    auto frag = [&](const unsigned short* lds, int row, int ks) -> bf16x8 {
        const int slot = ks ^ (row & 7);
        return *(const bf16x8*)((const char*)lds + row * (BK * 2) + slot * 16);
    };

    f32x4 acc[4][4] = {};

    stage(0);

    #pragma unroll
    for (int t = 0; t < NT; ++t) {
        asm volatile("s_waitcnt vmcnt(0)" ::: "memory");  // own slab-t chunks done
        __syncthreads();               // all waves' chunks visible; prev slab
                                       // fully consumed (reads precede barrier)
        if (t + 1 < NT) stage(t + 1);  // overwrites slab read at iter t-1: safe

        bf16x8 af[2][4], bf[2][4];
        #pragma unroll
        for (int h = 0; h < 2; ++h) {
            #pragma unroll
            for (int m = 0; m < 4; ++m)
                af[h][m] = frag(As[t & 1], wr + m * 16 + lr, h * 4 + ls);
            #pragma unroll
            for (int n = 0; n < 4; ++n)
                bf[h][n] = frag(Bs[t & 1], wc + n * 16 + lr, h * 4 + ls);
        }

        __builtin_amdgcn_s_setprio(1);
        #pragma unroll
        for (int h = 0; h < 2; ++h)
            #pragma unroll
            for (int m = 0; m < 4; ++m)
                #pragma unroll
                for (int n = 0; n < 4; ++n)
                    acc[m][n] = __builtin_amdgcn_mfma_f32_16x16x32_bf16(
                        af[h][m], bf[h][n], acc[m][n], 0, 0, 0);
        __builtin_amdgcn_s_setprio(0);
    }

    // epilogue: C/D layout col=lane&15, row=(lane>>4)*4+j (HW-verified)
    const int r0 = bm * BM + wr + ls * 4;
    const int c0 = bn * BN + wc + lr;
    #pragma unroll
    for (int n = 0; n < 4; ++n) {
        const int gc = c0 + n * 16;
        const float bv = bias[gc];
        #pragma unroll
        for (int m = 0; m < 4; ++m) {
            #pragma unroll
            for (int j = 0; j < 4; ++j) {
                const int gr = r0 + m * 16 + j;
                const float v = acc[m][n][j] + bv;
                if constexpr (OUT_BF16)
                    ((unsigned short*)Cvoid)[(size_t)gr * N + gc] = f2bf(v);
                else
                    ((float*)Cvoid)[(size_t)gr * N + gc] = v;
            }
        }
    }
}

// ---------------- per-token attention over heads (8x8 softmax) --------------
__global__ __launch_bounds__(256) void attn_heads(
        const unsigned short* __restrict__ qkv,   // [M][1536] bf16
        unsigned short* __restrict__ val,         // [M][512]  bf16
        int M) {
    const int t    = blockIdx.x * 4 + (threadIdx.x >> 6);
    const int lane = threadIdx.x & 63;
    const int h    = lane >> 3;
    const int c    = lane & 7;
    const unsigned short* base = qkv + (size_t)t * 1536;

    s16x8 q8 = *(const s16x8*)(base + h * 192 + c * 8);
    float qf[8];
    #pragma unroll
    for (int j = 0; j < 8; ++j) qf[j] = bf2f((unsigned short)q8[j]);

    float s[8];
    #pragma unroll
    for (int g = 0; g < 8; ++g) {
        s16x8 k8 = *(const s16x8*)(base + g * 192 + 64 + c * 8);
        float p = 0.f;
        #pragma unroll
        for (int j = 0; j < 8; ++j) p += qf[j] * bf2f((unsigned short)k8[j]);
        s[g] = p;
    }
    #pragma unroll
    for (int mask = 1; mask <= 4; mask <<= 1)
        #pragma unroll
        for (int g = 0; g < 8; ++g)
            s[g] += __shfl_xor(s[g], mask, 64);

    float mx = -1e30f;
    #pragma unroll
    for (int g = 0; g < 8; ++g) { s[g] *= 0.125f; mx = fmaxf(mx, s[g]); }
    float sum = 0.f;
    #pragma unroll
    for (int g = 0; g < 8; ++g) { s[g] = __expf(s[g] - mx); sum += s[g]; }
    const float inv = 1.f / sum;

    float acc[8] = {0.f,0.f,0.f,0.f,0.f,0.f,0.f,0.f};
    #pragma unroll
    for (int g = 0; g < 8; ++g) {
        s16x8 v8 = *(const s16x8*)(base + g * 192 + 128 + c * 8);
        const float ag = s[g] * inv;
        #pragma unroll
        for (int j = 0; j < 8; ++j) acc[j] += ag * bf2f((unsigned short)v8[j]);
    }
    s16x8 ov;
    #pragma unroll
    for (int j = 0; j < 8; ++j) ov[j] = (short)f2bf(acc[j]);
    *(s16x8*)(val + (size_t)t * 512 + h * 64 + c * 8) = ov;
}

// ---------------------------------------------------------------------------
extern "C" void kernel_launch(void* const* d_in, const int* in_sizes, int n_in,
                              void* d_out, int out_size, void* d_ws, size_t ws_size,
                              hipStream_t stream) {
    const float* x     = (const float*)d_in[0];
    const float* w_qkv = (const float*)d_in[1];
    const float* b_qkv = (const float*)d_in[2];
    const float* w_out = (const float*)d_in[3];
    const float* b_out = (const float*)d_in[4];
    float* out = (float*)d_out;

    const int DM = 512;
    const int M  = in_sizes[0] / DM;      // 61440 tokens

    unsigned short* xb    = (unsigned short*)d_ws;          // M*512
    unsigned short* wqkvb = xb + (size_t)M * DM;            // 1536*512
    unsigned short* woutb = wqkvb + (size_t)3 * DM * DM;    // 512*512
    unsigned short* qkvb  = woutb + (size_t)DM * DM;        // M*1536
    unsigned short* valb  = xb;   // reuse x_bf16 buffer after GEMM1 consumed it

    cvt_bf16<<<2048, 256, 0, stream>>>(x, xb, M * DM / 4);
    cvt_bf16<<<96,   256, 0, stream>>>(w_qkv, wqkvb, 3 * DM * DM / 4);
    cvt_bf16<<<32,   256, 0, stream>>>(w_out, woutb, DM * DM / 4);

    // GEMM1: qkv[M][1536] = x @ w_qkv^T + b_qkv (bf16 out). grid 480*12=5760
    gemm128<512, true><<<dim3((M / 128) * (3 * DM / 128)), 256, 0, stream>>>(
        xb, wqkvb, b_qkv, qkvb, M, 3 * DM, 3 * DM / 128);

    // per-token attention over heads
    attn_heads<<<M / 4, 256, 0, stream>>>(qkvb, valb, M);

    // GEMM2: out[M][512] = val @ w_out^T + b_out (fp32 out). grid 480*4=1920
    gemm128<512, false><<<dim3((M / 128) * (DM / 128)), 256, 0, stream>>>(
        valb, woutb, b_out, out, M, DM, DM / 128);
}